// Round 1
// baseline (499.323 us; speedup 1.0000x reference)
//
#include <hip/hip_runtime.h>
#include <cmath>

// GCNConv(C=256 -> 1, add_self_loops, symmetric norm) + Softplus
//
// Pipeline (5 kernels, all memory-bound):
//  K1: h[n] = dot(x[n,:], W)  (wave-per-node, float4 lanes) ; deg[n] = 1.0 (self-loop)
//  K2: deg[dst[e]] += 1       (float atomics, int4 edge loads)
//  K3: dinv = rsqrt(deg) -> deg ; g = dinv*h -> h ; acc = g (self-loop term)
//  K4: acc[dst[e]] += g[src[e]]  (gather+scatter, both arrays L2-resident: 400 KB)
//  K5: out[n] = softplus(dinv[n]*acc[n] + b)

__global__ void k1_linear_deginit(const float* __restrict__ x,
                                  const float* __restrict__ W,
                                  float* __restrict__ h,
                                  float* __restrict__ deg,
                                  int N) {
    int gtid = blockIdx.x * blockDim.x + threadIdx.x;
    int wave = gtid >> 6;          // one 64-lane wave per node row
    int lane = gtid & 63;
    if (wave >= N) return;
    const float4 xv = *reinterpret_cast<const float4*>(x + (size_t)wave * 256 + lane * 4);
    const float4 wv = *reinterpret_cast<const float4*>(W + lane * 4);
    float s = xv.x * wv.x + xv.y * wv.y + xv.z * wv.z + xv.w * wv.w;
    #pragma unroll
    for (int off = 32; off >= 1; off >>= 1)
        s += __shfl_xor(s, off, 64);
    if (lane == 0) {
        h[wave] = s;
        deg[wave] = 1.0f;   // self-loop
    }
}

__global__ void k2_degree(const int* __restrict__ dst,
                          float* __restrict__ deg, int E) {
    int stride = gridDim.x * blockDim.x;
    int E4 = E >> 2;
    const int4* d4 = reinterpret_cast<const int4*>(dst);
    for (int i = blockIdx.x * blockDim.x + threadIdx.x; i < E4; i += stride) {
        int4 v = d4[i];
        atomicAdd(&deg[v.x], 1.0f);
        atomicAdd(&deg[v.y], 1.0f);
        atomicAdd(&deg[v.z], 1.0f);
        atomicAdd(&deg[v.w], 1.0f);
    }
    for (int i = (E4 << 2) + blockIdx.x * blockDim.x + threadIdx.x; i < E; i += stride)
        atomicAdd(&deg[dst[i]], 1.0f);
}

__global__ void k3_prep(float* __restrict__ deg,   // in: deg, out: dinv
                        float* __restrict__ h,     // in: h,   out: g = dinv*h
                        float* __restrict__ acc,   // out: self-loop seed
                        int N) {
    int n = blockIdx.x * blockDim.x + threadIdx.x;
    if (n >= N) return;
    float dinv = rsqrtf(deg[n]);
    float g = dinv * h[n];
    deg[n] = dinv;
    h[n] = g;
    acc[n] = g;
}

__global__ void k4_scatter(const int* __restrict__ src,
                           const int* __restrict__ dst,
                           const float* __restrict__ g,
                           float* __restrict__ acc, int E) {
    int stride = gridDim.x * blockDim.x;
    int E4 = E >> 2;
    const int4* s4 = reinterpret_cast<const int4*>(src);
    const int4* d4 = reinterpret_cast<const int4*>(dst);
    for (int i = blockIdx.x * blockDim.x + threadIdx.x; i < E4; i += stride) {
        int4 sv = s4[i];
        int4 dv = d4[i];
        atomicAdd(&acc[dv.x], g[sv.x]);
        atomicAdd(&acc[dv.y], g[sv.y]);
        atomicAdd(&acc[dv.z], g[sv.z]);
        atomicAdd(&acc[dv.w], g[sv.w]);
    }
    for (int i = (E4 << 2) + blockIdx.x * blockDim.x + threadIdx.x; i < E; i += stride)
        atomicAdd(&acc[dst[i]], g[src[i]]);
}

__global__ void k5_final(const float* __restrict__ dinv,
                         const float* __restrict__ acc,
                         const float* __restrict__ b,
                         float* __restrict__ out, int N) {
    int n = blockIdx.x * blockDim.x + threadIdx.x;
    if (n >= N) return;
    float v = dinv[n] * acc[n] + b[0];
    // numerically-stable softplus = max(v,0) + log1p(exp(-|v|))
    out[n] = fmaxf(v, 0.0f) + log1pf(expf(-fabsf(v)));
}

extern "C" void kernel_launch(void* const* d_in, const int* in_sizes, int n_in,
                              void* d_out, int out_size, void* d_ws, size_t ws_size,
                              hipStream_t stream) {
    const float* x  = (const float*)d_in[0];
    const int*   ei = (const int*)d_in[1];
    const float* W  = (const float*)d_in[2];
    const float* b  = (const float*)d_in[3];
    float* out = (float*)d_out;

    int N = in_sizes[0] / 256;
    int E = in_sizes[1] / 2;
    const int* src = ei;
    const int* dst = ei + E;

    float* h   = (float*)d_ws;   // N floats
    float* deg = h + N;          // N floats
    float* acc = deg + N;        // N floats

    // K1: wave-per-node dot product + deg init
    int blocks1 = (N * 64 + 255) / 256;
    k1_linear_deginit<<<blocks1, 256, 0, stream>>>(x, W, h, deg, N);

    // K2: degree accumulation over dst
    int t4 = (E + 3) / 4;
    int blocks2 = min((t4 + 255) / 256, 2048);
    k2_degree<<<blocks2, 256, 0, stream>>>(dst, deg, E);

    // K3: dinv / g / self-loop seed
    int blocksN = (N + 255) / 256;
    k3_prep<<<blocksN, 256, 0, stream>>>(deg, h, acc, N);

    // K4: edge scatter
    k4_scatter<<<blocks2, 256, 0, stream>>>(src, dst, h, acc, E);

    // K5: finalize + softplus
    k5_final<<<blocksN, 256, 0, stream>>>(deg, acc, b, out, N);
}

// Round 2
// 458.666 us; speedup vs baseline: 1.0886x; 1.0886x over previous
//
#include <hip/hip_runtime.h>
#include <cmath>

// GCNConv(C=256 -> 1, add_self_loops, symmetric norm) + Softplus
//
//  memset: cnt = 0
//  K12 (fused): phase A: h[n] = dot(x[n,:], W)   (wave-per-row, float4 lanes)
//               phase B: cnt[dst[e]] += 1        (native u32 atomics)
//  K3: dinv = rsqrt(cnt+1) ; g = dinv*h ; acc = g (self-loop term)
//  K4: acc[dst[e]] += g[src[e]]   (unsafeAtomicAdd -> global_atomic_add_f32)
//  K5: out[n] = softplus(dinv*acc + b)

__global__ __launch_bounds__(256) void k12_fused(
        const float* __restrict__ x,
        const float* __restrict__ W,
        const int* __restrict__ dst,
        float* __restrict__ h,
        unsigned int* __restrict__ cnt,
        int N, int E) {
    int tid   = blockIdx.x * blockDim.x + threadIdx.x;
    int nthr  = gridDim.x * blockDim.x;
    int lane  = threadIdx.x & 63;

    // ---- phase A: one wave per node row, grid-stride over rows ----
    int wid    = tid >> 6;
    int nwaves = nthr >> 6;
    const float4 wv = *reinterpret_cast<const float4*>(W + lane * 4);
    for (int row = wid; row < N; row += nwaves) {
        const float4 xv = *reinterpret_cast<const float4*>(x + (size_t)row * 256 + lane * 4);
        float s = xv.x * wv.x + xv.y * wv.y + xv.z * wv.z + xv.w * wv.w;
        #pragma unroll
        for (int off = 32; off >= 1; off >>= 1)
            s += __shfl_xor(s, off, 64);
        if (lane == 0) h[row] = s;
    }

    // ---- phase B: degree histogram over dst (u32 atomics) ----
    int E4 = E >> 2;
    const int4* d4 = reinterpret_cast<const int4*>(dst);
    for (int i = tid; i < E4; i += nthr) {
        int4 v = d4[i];
        atomicAdd(&cnt[v.x], 1u);
        atomicAdd(&cnt[v.y], 1u);
        atomicAdd(&cnt[v.z], 1u);
        atomicAdd(&cnt[v.w], 1u);
    }
    for (int i = (E4 << 2) + tid; i < E; i += nthr)
        atomicAdd(&cnt[dst[i]], 1u);
}

__global__ __launch_bounds__(256) void k3_prep(
        const unsigned int* __restrict__ cnt,
        const float* __restrict__ h,
        float* __restrict__ dinv,
        float* __restrict__ g,
        float* __restrict__ acc,
        int N) {
    int n = blockIdx.x * blockDim.x + threadIdx.x;
    if (n >= N) return;
    float di = rsqrtf((float)(cnt[n] + 1u));   // +1 = self-loop
    float gg = di * h[n];
    dinv[n] = di;
    g[n]    = gg;
    acc[n]  = gg;                               // self-loop term: dinv*h (times dinv later)
}

__global__ __launch_bounds__(256) void k4_scatter(
        const int* __restrict__ src,
        const int* __restrict__ dst,
        const float* __restrict__ g,
        float* __restrict__ acc, int E) {
    int tid  = blockIdx.x * blockDim.x + threadIdx.x;
    int nthr = gridDim.x * blockDim.x;
    int E4 = E >> 2;
    const int4* s4 = reinterpret_cast<const int4*>(src);
    const int4* d4 = reinterpret_cast<const int4*>(dst);
    for (int i = tid; i < E4; i += nthr) {
        int4 sv = s4[i];
        int4 dv = d4[i];
        float g0 = g[sv.x], g1 = g[sv.y], g2 = g[sv.z], g3 = g[sv.w];
        unsafeAtomicAdd(&acc[dv.x], g0);
        unsafeAtomicAdd(&acc[dv.y], g1);
        unsafeAtomicAdd(&acc[dv.z], g2);
        unsafeAtomicAdd(&acc[dv.w], g3);
    }
    for (int i = (E4 << 2) + tid; i < E; i += nthr)
        unsafeAtomicAdd(&acc[dst[i]], g[src[i]]);
}

__global__ __launch_bounds__(256) void k5_final(
        const float* __restrict__ dinv,
        const float* __restrict__ acc,
        const float* __restrict__ b,
        float* __restrict__ out, int N) {
    int n = blockIdx.x * blockDim.x + threadIdx.x;
    if (n >= N) return;
    float v = dinv[n] * acc[n] + b[0];
    out[n] = fmaxf(v, 0.0f) + log1pf(expf(-fabsf(v)));   // stable softplus
}

extern "C" void kernel_launch(void* const* d_in, const int* in_sizes, int n_in,
                              void* d_out, int out_size, void* d_ws, size_t ws_size,
                              hipStream_t stream) {
    const float* x  = (const float*)d_in[0];
    const int*   ei = (const int*)d_in[1];
    const float* W  = (const float*)d_in[2];
    const float* b  = (const float*)d_in[3];
    float* out = (float*)d_out;

    int N = in_sizes[0] / 256;
    int E = in_sizes[1] / 2;
    const int* src = ei;
    const int* dst = ei + E;

    float*        h    = (float*)d_ws;                 // N
    float*        dinv = h + N;                        // N
    float*        g    = dinv + N;                     // N
    float*        acc  = g + N;                        // N
    unsigned int* cnt  = (unsigned int*)(acc + N);     // N

    hipMemsetAsync(cnt, 0, (size_t)N * sizeof(unsigned int), stream);

    // fused row-dot + degree histogram: 2048 blocks = full residency
    k12_fused<<<2048, 256, 0, stream>>>(x, W, dst, h, cnt, N, E);

    int blocksN = (N + 255) / 256;
    k3_prep<<<blocksN, 256, 0, stream>>>(cnt, h, dinv, g, acc, N);

    k4_scatter<<<2048, 256, 0, stream>>>(src, dst, g, acc, E);

    k5_final<<<blocksN, 256, 0, stream>>>(dinv, acc, b, out, N);
}